// Round 2
// baseline (644.626 us; speedup 1.0000x reference)
//
#include <hip/hip_runtime.h>
#include <hip/hip_bf16.h>

typedef __attribute__((ext_vector_type(8))) short bf16x8;
typedef __attribute__((ext_vector_type(4))) float f32x4;

#define KCAT 9216            // 1024 base cols + 1024*8 spline cols
#define NTOK 8192
#define CH   1024

// ---------- helpers ----------
__device__ __forceinline__ unsigned short f2bf(float f) {
    union { float f; unsigned int u; } v; v.f = f;
    unsigned int r = v.u + 0x7fffu + ((v.u >> 16) & 1u);   // RNE
    return (unsigned short)(r >> 16);
}

__device__ __forceinline__ void load16_to_lds(const void* gp, void* lp) {
    __builtin_amdgcn_global_load_lds(
        (__attribute__((address_space(1))) void*)(void*)gp,
        (__attribute__((address_space(3))) void*)lp,
        16, 0, 0);
}

// ---------- weight pack: [out,1024] f32 + [out,1024,8] f32 -> [out, 9216] bf16 ----------
__global__ __launch_bounds__(256) void conv_w(const float* __restrict__ BW,
                                              const float* __restrict__ SW,
                                              unsigned short* __restrict__ W) {
    int o = blockIdx.x;
    const float* bw = BW + (size_t)o * 1024;
    const float* sw = SW + (size_t)o * 8192;
    unsigned short* w = W + (size_t)o * KCAT;
    for (int c = threadIdx.x * 4; c < KCAT; c += 256 * 4) {
        const float* src = (c < 1024) ? (bw + c) : (sw + (c - 1024));
        float4 v = *(const float4*)src;
        unsigned short u[4] = { f2bf(v.x), f2bf(v.y), f2bf(v.z), f2bf(v.w) };
        *(unsigned long long*)(w + c) = *(unsigned long long*)u;
    }
}

// ---------- basis expansion: X [8192,1024] f32 -> A [8192,9216] bf16 ----------
// A[n][i]           = bf16(x[n][i])                      (base part)
// A[n][1024+i*8+k]  = bf16(B_k(x[n][i]))                 (spline part)
__global__ __launch_bounds__(256) void kan_basis(const float* __restrict__ X,
                                                 unsigned short* __restrict__ A,
                                                 int total) {
    const float h = 0.08f;
    float t[12];
#pragma unroll
    for (int j = 0; j < 12; ++j) t[j] = -0.2f + h * (float)(j - 3);
    const float r1 = 1.0f / h;
    const float r2 = 1.0f / (2.0f * h);
    const float r3 = 1.0f / (3.0f * h);

    for (int idx = blockIdx.x * 256 + threadIdx.x; idx < total; idx += gridDim.x * 256) {
        int n = idx >> 10;
        int i = idx & 1023;
        float x = X[idx];
        size_t rowbase = (size_t)n * KCAT;
        A[rowbase + i] = f2bf(x);

        float b[11];
#pragma unroll
        for (int j = 0; j < 11; ++j)
            b[j] = (x >= t[j] && x < t[j + 1]) ? 1.0f : 0.0f;
#pragma unroll
        for (int j = 0; j < 10; ++j)
            b[j] = (x - t[j]) * r1 * b[j] + (t[j + 2] - x) * r1 * b[j + 1];
#pragma unroll
        for (int j = 0; j < 9; ++j)
            b[j] = (x - t[j]) * r2 * b[j] + (t[j + 3] - x) * r2 * b[j + 1];
#pragma unroll
        for (int j = 0; j < 8; ++j)
            b[j] = (x - t[j]) * r3 * b[j] + (t[j + 4] - x) * r3 * b[j + 1];

        unsigned short out8[8];
#pragma unroll
        for (int j = 0; j < 8; ++j) out8[j] = f2bf(b[j]);
        *(bf16x8*)(A + rowbase + 1024 + (size_t)i * 8) = *(bf16x8*)out8;
    }
}

// ---------- GEMM: C[M,N] f32 = A[M,K]bf16 (K-major) @ B[N,K]bf16 (K-major)^T ----------
// m97 structure: 128x128 tile, 4 waves (2x2), BK=64, global_load_lds width 16.
__global__ __launch_bounds__(256) void gemm_bt(const unsigned short* __restrict__ A,
                                               const unsigned short* __restrict__ B,
                                               float* __restrict__ C,
                                               int M, int N, int K) {
    __shared__ unsigned short As[128 * 64];
    __shared__ unsigned short Bs[128 * 64];
    const int tid  = threadIdx.x;
    const int lane = tid & 63;
    const int wave = tid >> 6;
    const int bn = blockIdx.x, bm = blockIdx.y;   // bn fast-varying: A-panel L2/LLC reuse
    const int row0 = bm * 128, col0 = bn * 128;
    const int wm = (wave >> 1) * 64, wn = (wave & 1) * 64;
    const int ln = lane & 15, q = lane >> 4;

    f32x4 acc[4][4] = {};

    for (int k0 = 0; k0 < K; k0 += 64) {
        const char* Ab = (const char*)(A + (size_t)row0 * K + k0);
        const char* Bb = (const char*)(B + (size_t)col0 * K + k0);
#pragma unroll
        for (int it = 0; it < 4; ++it) {
            int chunk = it * 256 + tid;          // 0..1023, lds dest = chunk*16B
            int r  = chunk >> 3;                 // tile row 0..127
            int cb = (chunk & 7) * 16;           // byte offset within 128B row
            load16_to_lds(Ab + (size_t)r * (K * 2) + cb, (char*)As + chunk * 16);
            load16_to_lds(Bb + (size_t)r * (K * 2) + cb, (char*)Bs + chunk * 16);
        }
        __syncthreads();                         // drains vmcnt (global_load_lds) too
#pragma unroll
        for (int kk = 0; kk < 2; ++kk) {
            bf16x8 af[4], bg[4];
#pragma unroll
            for (int m = 0; m < 4; ++m)
                af[m] = *(const bf16x8*)&As[(wm + m * 16 + ln) * 64 + kk * 32 + q * 8];
#pragma unroll
            for (int n = 0; n < 4; ++n)
                bg[n] = *(const bf16x8*)&Bs[(wn + n * 16 + ln) * 64 + kk * 32 + q * 8];
#pragma unroll
            for (int m = 0; m < 4; ++m)
#pragma unroll
                for (int n = 0; n < 4; ++n)
                    acc[m][n] = __builtin_amdgcn_mfma_f32_16x16x32_bf16(af[m], bg[n], acc[m][n], 0, 0, 0);
        }
        __syncthreads();
    }

    // epilogue: C/D layout col=lane&15, row=(lane>>4)*4+reg   [m89-verified]
#pragma unroll
    for (int m = 0; m < 4; ++m)
#pragma unroll
        for (int n = 0; n < 4; ++n)
#pragma unroll
            for (int r = 0; r < 4; ++r) {
                int row = row0 + wm + m * 16 + q * 4 + r;
                int col = col0 + wn + n * 16 + ln;
                C[(size_t)row * N + col] = acc[m][n][r];
            }
}

// ---------- launch ----------
extern "C" void kernel_launch(void* const* d_in, const int* in_sizes, int n_in,
                              void* d_out, int out_size, void* d_ws, size_t ws_size,
                              hipStream_t stream) {
    const float* x   = (const float*)d_in[0];
    const float* bw1 = (const float*)d_in[1];
    const float* sw1 = (const float*)d_in[2];
    const float* bw2 = (const float*)d_in[3];
    const float* sw2 = (const float*)d_in[4];
    float* out = (float*)d_out;

    char* ws = (char*)d_ws;
    unsigned short* Abuf = (unsigned short*)ws;                            // 8192*9216*2   = 150,994,944 B
    float*          X1   = (float*)(ws + 150994944);                       // 8192*1024*4   =  33,554,432 B
    unsigned short* Wbuf = (unsigned short*)(ws + 150994944 + 33554432);   // 1024*9216*2   =  18,874,368 B

    dim3 blk(256);
    dim3 gW(1024);
    dim3 gB(2048);
    dim3 gG(CH / 128, NTOK / 128);   // (8, 64), bn fast

    // layer 1
    conv_w   <<<gW, blk, 0, stream>>>(bw1, sw1, Wbuf);
    kan_basis<<<gB, blk, 0, stream>>>(x, Abuf, NTOK * CH);
    gemm_bt  <<<gG, blk, 0, stream>>>(Abuf, Wbuf, X1, NTOK, CH, KCAT);

    // layer 2 (reuse Abuf/Wbuf; stream-ordered so no hazard)
    conv_w   <<<gW, blk, 0, stream>>>(bw2, sw2, Wbuf);
    kan_basis<<<gB, blk, 0, stream>>>(X1, Abuf, NTOK * CH);
    gemm_bt  <<<gG, blk, 0, stream>>>(Abuf, Wbuf, out, NTOK, CH, KCAT);
}

// Round 4
// 506.666 us; speedup vs baseline: 1.2723x; 1.2723x over previous
//
#include <hip/hip_runtime.h>
#include <hip/hip_bf16.h>

typedef __attribute__((ext_vector_type(8))) short bf16x8;
typedef __attribute__((ext_vector_type(4))) float f32x4;

#define KCAT 9216            // 1024 base cols + 1024*8 spline cols
#define NTOK 8192
#define CH   1024
#define KHALF 4608           // split-K half
#define BK   64
#define NT   (KHALF / BK)    // 72 K-tiles per block

// ---------- helpers ----------
__device__ __forceinline__ unsigned short f2bf(float f) {
    union { float f; unsigned int u; } v; v.f = f;
    unsigned int r = v.u + 0x7fffu + ((v.u >> 16) & 1u);   // RNE
    return (unsigned short)(r >> 16);
}

__device__ __forceinline__ void load16_to_lds(const void* gp, void* lp) {
    __builtin_amdgcn_global_load_lds(
        (__attribute__((address_space(1))) void*)(void*)gp,
        (__attribute__((address_space(3))) void*)lp,
        16, 0, 0);
}

// Cox-de Boor: 8 cubic B-spline bases for x on the fixed KAN grid
__device__ __forceinline__ void bases8(float x, unsigned short* out8) {
    const float h = 0.08f;
    float t[12];
#pragma unroll
    for (int j = 0; j < 12; ++j) t[j] = -0.2f + h * (float)(j - 3);
    const float r1 = 1.0f / h, r2 = 1.0f / (2.0f * h), r3 = 1.0f / (3.0f * h);
    float b[11];
#pragma unroll
    for (int j = 0; j < 11; ++j) b[j] = (x >= t[j] && x < t[j + 1]) ? 1.0f : 0.0f;
#pragma unroll
    for (int j = 0; j < 10; ++j) b[j] = (x - t[j]) * r1 * b[j] + (t[j + 2] - x) * r1 * b[j + 1];
#pragma unroll
    for (int j = 0; j < 9; ++j)  b[j] = (x - t[j]) * r2 * b[j] + (t[j + 3] - x) * r2 * b[j + 1];
#pragma unroll
    for (int j = 0; j < 8; ++j)  b[j] = (x - t[j]) * r3 * b[j] + (t[j + 4] - x) * r3 * b[j + 1];
#pragma unroll
    for (int j = 0; j < 8; ++j) out8[j] = f2bf(b[j]);
}

// ---------- weight pack: [out,1024] f32 + [out,1024,8] f32 -> [out, 9216] bf16 ----------
__global__ __launch_bounds__(256) void conv_w(const float* __restrict__ BW,
                                              const float* __restrict__ SW,
                                              unsigned short* __restrict__ W) {
    int o = blockIdx.x;
    const float* bw = BW + (size_t)o * 1024;
    const float* sw = SW + (size_t)o * 8192;
    unsigned short* w = W + (size_t)o * KCAT;
    for (int c = threadIdx.x * 4; c < KCAT; c += 256 * 4) {
        const float* src = (c < 1024) ? (bw + c) : (sw + (c - 1024));
        float4 v = *(const float4*)src;
        unsigned short u[4] = { f2bf(v.x), f2bf(v.y), f2bf(v.z), f2bf(v.w) };
        *(unsigned long long*)(w + c) = *(unsigned long long*)u;
    }
}

// ---------- basis expansion from f32 x ----------
__global__ __launch_bounds__(256) void kan_basis_x(const float* __restrict__ X,
                                                   unsigned short* __restrict__ A,
                                                   int total) {
    for (int idx = blockIdx.x * 256 + threadIdx.x; idx < total; idx += gridDim.x * 256) {
        int n = idx >> 10, i = idx & 1023;
        float x = X[idx];
        size_t rowbase = (size_t)n * KCAT;
        A[rowbase + i] = f2bf(x);
        unsigned short out8[8];
        bases8(x, out8);
        *(bf16x8*)(A + rowbase + 1024 + (size_t)i * 8) = *(bf16x8*)out8;
    }
}

// ---------- basis expansion fused with split-K reduction (layer-2 input) ----------
__global__ __launch_bounds__(256) void kan_basis_sum(const float* __restrict__ C0,
                                                     const float* __restrict__ C1,
                                                     unsigned short* __restrict__ A,
                                                     int total) {
    for (int idx = blockIdx.x * 256 + threadIdx.x; idx < total; idx += gridDim.x * 256) {
        int n = idx >> 10, i = idx & 1023;
        float x = C0[idx] + C1[idx];
        size_t rowbase = (size_t)n * KCAT;
        A[rowbase + i] = f2bf(x);
        unsigned short out8[8];
        bases8(x, out8);
        *(bf16x8*)(A + rowbase + 1024 + (size_t)i * 8) = *(bf16x8*)out8;
    }
}

// ---------- final split-K reduction ----------
__global__ __launch_bounds__(256) void add_out(const float* __restrict__ C0,
                                               const float* __restrict__ C1,
                                               float* __restrict__ out, int total4) {
    for (int i = blockIdx.x * 256 + threadIdx.x; i < total4; i += gridDim.x * 256) {
        float4 a = ((const float4*)C0)[i];
        float4 b = ((const float4*)C1)[i];
        float4 r = { a.x + b.x, a.y + b.y, a.z + b.z, a.w + b.w };
        ((float4*)out)[i] = r;
    }
}

// ---------- 256x256 8-phase split-K GEMM ----------
// C[kz][M,N] f32 = A[M, kz-half of K] bf16 @ B[N, kz-half]^T
// 512 thr = 8 waves (2M x 4N); per-wave 128x64 out; BK=64; 4 phases/K-tile.
// LDS: 2 x (A 256x64 + B 256x64) bf16 = 128 KiB. XOR slot swizzle (T2, rule 21):
// stage writes linear LDS from inverse-swizzled global source; reads apply same XOR.
__global__ __launch_bounds__(512, 2) void gemm256_splitk(const unsigned short* __restrict__ A,
                                                         const unsigned short* __restrict__ B,
                                                         float* __restrict__ C0,
                                                         float* __restrict__ C1) {
    __shared__ unsigned short As[2 * 256 * 64];
    __shared__ unsigned short Bs[2 * 256 * 64];
    const int tid  = threadIdx.x;
    const int lane = tid & 63;
    const int wid  = tid >> 6;
    const int wr = wid >> 2, wc = wid & 3;       // wave grid 2(M) x 4(N)
    const int ln = lane & 15, q = lane >> 4;

    // XCD-aware decode (perf heuristic only): xcd = bid%8 gets one (kz, bm-chunk),
    // all 4 bn -> per-XCD L2 set ~= 8 A-panels (18.9MB) + 4 W-panels (9.4MB).
    const int bid = blockIdx.x;                  // 0..255
    const int xcd = bid & 7, i = bid >> 3;       // i: 0..31
    const int kz = xcd & 1, chm = xcd >> 1;      // chm: 0..3
    const int bm = chm * 8 + (i & 7);            // 0..31
    const int bn = i >> 3;                       // 0..3

    const unsigned short* Ab = A + (size_t)(bm * 256) * KCAT + (size_t)kz * KHALF;
    const unsigned short* Bb = B + (size_t)(bn * 256) * KCAT + (size_t)kz * KHALF;
    float* C = (kz == 0) ? C0 : C1;

    f32x4 acc[8][4] = {};

    // stage one quarter (part) of next tile: 512thr x 16B = 8KB A + 8KB B
    auto stage = [&](int t, int buf, int part) {
        int chunk = part * 512 + tid;            // 0..2047 over 4 parts
        int r    = chunk >> 3;                   // row 0..255
        int slot = (chunk & 7) ^ (r & 7);        // inverse swizzle on SOURCE
        size_t goff = (size_t)r * (KCAT * 2) + (size_t)t * (BK * 2) + slot * 16;
        load16_to_lds((const char*)Ab + goff, (char*)As + (size_t)buf * 32768 + chunk * 16);
        load16_to_lds((const char*)Bb + goff, (char*)Bs + (size_t)buf * 32768 + chunk * 16);
    };

    // prologue: tile 0 -> buf 0
    stage(0, 0, 0); stage(0, 0, 1); stage(0, 0, 2); stage(0, 0, 3);
    asm volatile("s_waitcnt vmcnt(0)" ::: "memory");
    __builtin_amdgcn_s_barrier();

    for (int t = 0; t < NT; ++t) {
        const int c = t & 1;
        const char* Ap = (const char*)As + c * 32768;
        const char* Bp = (const char*)Bs + c * 32768;
        bf16x8 bfr[4][2];
        const bool pref = (t + 1 < NT);
#pragma unroll
        for (int p = 0; p < 4; ++p) {
            // ds-reads for this phase (swizzled byte offset)
            bf16x8 afr[2][2];
#pragma unroll
            for (int m2 = 0; m2 < 2; ++m2)
#pragma unroll
                for (int kh = 0; kh < 2; ++kh) {
                    int row = wr * 128 + (p * 2 + m2) * 16 + ln;
                    int byte = row * 128 + ((kh * 64 + q * 16) ^ ((row & 7) * 16));
                    afr[m2][kh] = *(const bf16x8*)(Ap + byte);
                }
            if (p == 0) {
#pragma unroll
                for (int nf = 0; nf < 4; ++nf)
#pragma unroll
                    for (int kh = 0; kh < 2; ++kh) {
                        int row = wc * 64 + nf * 16 + ln;
                        int byte = row * 128 + ((kh * 64 + q * 16) ^ ((row & 7) * 16));
                        bfr[nf][kh] = *(const bf16x8*)(Bp + byte);
                    }
            }
            // stage next tile: parts at phases 0,0,1,2 so youngest load gets ~2 phases
            if (pref) {
                if (p == 0)      { stage(t + 1, c ^ 1, 0); stage(t + 1, c ^ 1, 1); }
                else if (p == 1) { stage(t + 1, c ^ 1, 2); }
                else if (p == 2) { stage(t + 1, c ^ 1, 3); }
            }
            __builtin_amdgcn_s_barrier();
            asm volatile("s_waitcnt lgkmcnt(0)" ::: "memory");
            __builtin_amdgcn_sched_barrier(0);
            __builtin_amdgcn_s_setprio(1);
#pragma unroll
            for (int m2 = 0; m2 < 2; ++m2)
#pragma unroll
                for (int nf = 0; nf < 4; ++nf)
#pragma unroll
                    for (int kh = 0; kh < 2; ++kh)
                        acc[p * 2 + m2][nf] = __builtin_amdgcn_mfma_f32_16x16x32_bf16(
                            afr[m2][kh], bfr[nf][kh], acc[p * 2 + m2][nf], 0, 0, 0);
            __builtin_amdgcn_s_setprio(0);
            if (p == 3)  // publish next buffer: all waves' stage loads landed
                asm volatile("s_waitcnt vmcnt(0)" ::: "memory");
            __builtin_amdgcn_s_barrier();
        }
    }

    // epilogue: C/D layout col=lane&15, row=(lane>>4)*4+reg [m89-verified]
#pragma unroll
    for (int mf = 0; mf < 8; ++mf)
#pragma unroll
        for (int nf = 0; nf < 4; ++nf)
#pragma unroll
            for (int r = 0; r < 4; ++r) {
                int row = bm * 256 + wr * 128 + mf * 16 + q * 4 + r;
                int col = bn * 256 + wc * 64 + nf * 16 + ln;
                C[(size_t)row * CH + col] = acc[mf][nf][r];
            }
}

// ---------- launch ----------
extern "C" void kernel_launch(void* const* d_in, const int* in_sizes, int n_in,
                              void* d_out, int out_size, void* d_ws, size_t ws_size,
                              hipStream_t stream) {
    const float* x   = (const float*)d_in[0];
    const float* bw1 = (const float*)d_in[1];
    const float* sw1 = (const float*)d_in[2];
    const float* bw2 = (const float*)d_in[3];
    const float* sw2 = (const float*)d_in[4];
    float* out = (float*)d_out;

    char* ws = (char*)d_ws;
    unsigned short* Abuf = (unsigned short*)ws;                    // 150,994,944 B
    unsigned short* Wbuf = (unsigned short*)(ws + 150994944);      //  18,874,368 B
    float* C0 = (float*)(ws + 150994944 + 18874368);               //  33,554,432 B
    float* C1 = (float*)(ws + 150994944 + 18874368 + 33554432);    //  33,554,432 B

    dim3 blk(256);
    dim3 gW(1024);
    dim3 gB(2048);
    dim3 gG(256);
    dim3 blkG(512);

    // layer 1
    conv_w        <<<gW, blk, 0, stream>>>(bw1, sw1, Wbuf);
    kan_basis_x   <<<gB, blk, 0, stream>>>(x, Abuf, NTOK * CH);
    gemm256_splitk<<<gG, blkG, 0, stream>>>(Abuf, Wbuf, C0, C1);

    // layer 2 (split-K reduce fused into basis expansion)
    conv_w        <<<gW, blk, 0, stream>>>(bw2, sw2, Wbuf);
    kan_basis_sum <<<gB, blk, 0, stream>>>(C0, C1, Abuf, NTOK * CH);
    gemm256_splitk<<<gG, blkG, 0, stream>>>(Abuf, Wbuf, C0, C1);
    add_out       <<<dim3(1024), blk, 0, stream>>>(C0, C1, out, NTOK * CH / 4);
}